// Round 6
// baseline (130.272 us; speedup 1.0000x reference)
//
#include <hip/hip_runtime.h>

// GAT layer, N=8192, IN_F=512, OUT_F=64, alpha=0.2
// exp(lrelu(s1_i+s2_j)) factors on each side of s2_j <= -s1_i =>
// row_i = [A_i*suffixsum(exp(s2)*Wh) + B_i*prefixsum(exp(.2 s2)*Wh)] / (scalars)
// over s2 sorted ascending. O(N*F).
// Single cooperative kernel; the two global deps (s2->sorted, sorted+Wh->out)
// are crossed with 3-level XCD-aware tree barriers (flat 1-line barrier
// measured ~40us in R4 = 512 serialized same-line L3 RMWs; tree spreads the
// RMWs over 64 lines -> predicted ~4us).

constexpr int NV  = 8192;
constexpr int FIN = 512;
constexpr int NT  = 512;      // threads/block
constexpr int CH  = 16;       // sorted positions per chunk
constexpr int NB  = 512;      // blocks

__device__ __forceinline__ unsigned f2key(float x) {
    unsigned b = __float_as_uint(x);
    return (b & 0x80000000u) ? ~b : (b | 0x80000000u);  // order-preserving
}

// 3-level tree barrier. base layout (dwords): c1[64] at g*16, c2[8] at
// 1024+g*16, c3 at 1152. blockIdx&63 fixes blockIdx%8 (=XCD under round-robin)
// so each c1 group's 8 RMWs come from one XCD; 64 distinct lines in parallel.
__device__ __forceinline__ void gbar3(unsigned* base) {
    __syncthreads();   // all waves of this block done with the phase
    if (threadIdx.x == 0) {
        const unsigned b = (unsigned)blockIdx.x;
        const unsigned r1 = __hip_atomic_fetch_add(base + (b & 63u) * 16u, 1u,
                                 __ATOMIC_ACQ_REL, __HIP_MEMORY_SCOPE_AGENT);
        if (r1 == 7u) {          // last of my 8-block group
            const unsigned r2 = __hip_atomic_fetch_add(base + 1024u + (b & 7u) * 16u, 1u,
                                     __ATOMIC_ACQ_REL, __HIP_MEMORY_SCOPE_AGENT);
            if (r2 == 7u)        // last leader of my 8-group cluster
                __hip_atomic_fetch_add(base + 1152u, 1u,
                                       __ATOMIC_ACQ_REL, __HIP_MEMORY_SCOPE_AGENT);
        }
        while (__hip_atomic_load(base + 1152u, __ATOMIC_RELAXED,
                                 __HIP_MEMORY_SCOPE_AGENT) == 0u)
            __builtin_amdgcn_s_sleep(1);
        (void)__hip_atomic_load(base + 1152u, __ATOMIC_ACQUIRE,
                                __HIP_MEMORY_SCOPE_AGENT);  // inv L1/L2
    }
    __syncthreads();
}

__global__ __launch_bounds__(NT, 4) void gat3(
    const float* __restrict__ h, const float* __restrict__ W,
    const float* __restrict__ a, float* __restrict__ out,
    float* __restrict__ Wh, float* __restrict__ s1, float* __restrict__ s2g,
    int* __restrict__ sortedIdx, unsigned* __restrict__ sortedKey,
    float* __restrict__ sortedU, float* __restrict__ sortedV,
    unsigned* __restrict__ bar, int coopMode, int phaseLo, int phaseHi)
{
    // one LDS pool, aliased per phase (74.3 KB -> 2 blocks/CU)
    __shared__ __align__(16) unsigned char lds[74352];
    const int t = threadIdx.x, b = blockIdx.x;
    const int lane = t & 63, w = t >> 6;

    // ================= P0: Wh = h @ W^T ; s1 ; s2 =========================
    if (phaseLo <= 0 && 0 <= phaseHi) {
        float4* S4 = reinterpret_cast<float4*>(lds);   // 32 KB W-chunk
        const int row0 = __builtin_amdgcn_readfirstlane(b * 16 + w * 2);
        float4 A0 = {0.f,0.f,0.f,0.f}, A1 = {0.f,0.f,0.f,0.f};
        const float4* Wf4 = reinterpret_cast<const float4*>(W);
        for (int pass = 0; pass < 4; ++pass) {
            #pragma unroll
            for (int it = 0; it < 4; ++it) {
                const int g = it * 512 + t;          // 0..2047
                const int f = g >> 5, kk4 = g & 31;
                S4[kk4 * 64 + ((f + kk4) & 63)] = Wf4[f * 128 + pass * 32 + kk4];
            }
            __syncthreads();
            const float* hb = h + (size_t)row0 * FIN + pass * 128;
            #pragma unroll 8
            for (int k4 = 0; k4 < 32; ++k4) {
                const float4 wv = S4[k4 * 64 + ((lane + k4) & 63)];
                const float4 h0 = *reinterpret_cast<const float4*>(hb + k4 * 4);
                const float4 h1 = *reinterpret_cast<const float4*>(hb + FIN + k4 * 4);
                A0.x = fmaf(h0.x, wv.x, A0.x); A0.y = fmaf(h0.y, wv.y, A0.y);
                A0.z = fmaf(h0.z, wv.z, A0.z); A0.w = fmaf(h0.w, wv.w, A0.w);
                A1.x = fmaf(h1.x, wv.x, A1.x); A1.y = fmaf(h1.y, wv.y, A1.y);
                A1.z = fmaf(h1.z, wv.z, A1.z); A1.w = fmaf(h1.w, wv.w, A1.w);
            }
            __syncthreads();
        }
        const float acc0 = (A0.x + A0.y) + (A0.z + A0.w);
        const float acc1 = (A1.x + A1.y) + (A1.z + A1.w);
        Wh[(size_t)row0 * 64 + lane] = acc0;
        Wh[(size_t)(row0 + 1) * 64 + lane] = acc1;
        const float a1 = a[lane], a2 = a[64 + lane];
        float r0s1 = acc0 * a1, r0s2 = acc0 * a2;
        float r1s1 = acc1 * a1, r1s2 = acc1 * a2;
        #pragma unroll
        for (int off = 32; off > 0; off >>= 1) {
            r0s1 += __shfl_xor(r0s1, off);
            r0s2 += __shfl_xor(r0s2, off);
            r1s1 += __shfl_xor(r1s1, off);
            r1s2 += __shfl_xor(r1s2, off);
        }
        if (lane == 0) {
            s1[row0] = r0s1;     s2g[row0] = r0s2;
            s1[row0 + 1] = r1s1; s2g[row0 + 1] = r1s2;
        }
    }
    if (coopMode) gbar3(bar);

    // ================= P1: rank by unique key, scatter sorted arrays ======
    if (phaseLo <= 1 && 1 <= phaseHi) {
        unsigned* ks = reinterpret_cast<unsigned*>(lds);   // 32 KB keys
        #pragma unroll
        for (int q = 0; q < NV / NT; ++q) {
            const int j = q * NT + t;
            ks[j] = (f2key(s2g[j]) & 0xFFFFE000u) | (unsigned)j;  // unique keys
        }
        __syncthreads();
        const int seg = t & 31;             // 32 threads per id
        const int id  = b * 16 + (t >> 5);
        const unsigned key = ks[id];
        int cnt = 0;
        const uint4* K4 = reinterpret_cast<const uint4*>(ks);
        #pragma unroll 4
        for (int kk = 0; kk < 64; ++kk) {
            const uint4 v = K4[kk * 32 + seg];        // contiguous across lanes
            cnt += (int)(v.x < key) + (int)(v.y < key)
                 + (int)(v.z < key) + (int)(v.w < key);
        }
        cnt += __shfl_xor(cnt, 1);
        cnt += __shfl_xor(cnt, 2);
        cnt += __shfl_xor(cnt, 4);
        cnt += __shfl_xor(cnt, 8);
        cnt += __shfl_xor(cnt, 16);
        if (seg == 0) {
            sortedKey[cnt] = key;
            sortedIdx[cnt] = id;
            const float x = s2g[id];
            sortedU[cnt] = __expf(x);
            sortedV[cnt] = __expf(0.2f * x);
        }
    }
    if (coopMode) gbar3(bar + 2048);

    // ================= P2: block = (feature-slice, row-group) =============
    if (phaseLo <= 2 && 2 <= phaseHi) {
        unsigned* kss = reinterpret_cast<unsigned*>(lds);            // 32 KB
        float* Us    = reinterpret_cast<float*>(lds + 32768);  // [514][8]
        float* Vp    = reinterpret_cast<float*>(lds + 49216);  // [513][8]
        float* sus   = reinterpret_cast<float*>(lds + 65632);  // [514]
        float* svp   = reinterpret_cast<float*>(lds + 67688);  // [513]
        float* segTU = reinterpret_cast<float*>(lds + 69740);  // [64][8]
        float* segTV = reinterpret_cast<float*>(lds + 71788);  // [64][8]
        float* segSU = reinterpret_cast<float*>(lds + 73836);  // [64]
        float* segSV = reinterpret_cast<float*>(lds + 74092);  // [64]

        const int fid = b & 7;
        const int rg  = b >> 3;

        #pragma unroll
        for (int q = 0; q < NV / NT; ++q) kss[q * NT + t] = sortedKey[q * NT + t];

        // chunk sums: thread t owns chunk t (16 positions) for 8 features
        {
            float au[8] = {0.f,0.f,0.f,0.f,0.f,0.f,0.f,0.f};
            float av[8] = {0.f,0.f,0.f,0.f,0.f,0.f,0.f,0.f};
            float su = 0.f, sv = 0.f;
            const int p0 = t * CH;
            for (int q = 0; q < CH; ++q) {
                const int p = p0 + q;
                const int j = sortedIdx[p];
                const float u = sortedU[p];
                const float v = sortedV[p];
                const float4 w0 = *reinterpret_cast<const float4*>(Wh + (size_t)j * 64 + fid * 8);
                const float4 w1 = *reinterpret_cast<const float4*>(Wh + (size_t)j * 64 + fid * 8 + 4);
                au[0]=fmaf(u,w0.x,au[0]); au[1]=fmaf(u,w0.y,au[1]);
                au[2]=fmaf(u,w0.z,au[2]); au[3]=fmaf(u,w0.w,au[3]);
                au[4]=fmaf(u,w1.x,au[4]); au[5]=fmaf(u,w1.y,au[5]);
                au[6]=fmaf(u,w1.z,au[6]); au[7]=fmaf(u,w1.w,au[7]);
                av[0]=fmaf(v,w0.x,av[0]); av[1]=fmaf(v,w0.y,av[1]);
                av[2]=fmaf(v,w0.z,av[2]); av[3]=fmaf(v,w0.w,av[3]);
                av[4]=fmaf(v,w1.x,av[4]); av[5]=fmaf(v,w1.y,av[5]);
                av[6]=fmaf(v,w1.z,av[6]); av[7]=fmaf(v,w1.w,av[7]);
                su += u; sv += v;
            }
            #pragma unroll
            for (int e = 0; e < 8; ++e) { Us[t * 8 + e] = au[e]; Vp[t * 8 + e] = av[e]; }
            sus[t] = su; svp[t] = sv;
        }
        __syncthreads();

        // first-level scans (in place): thread -> (f, seg of 8 chunks)
        const int f = t & 7, seg = t >> 3;    // seg 0..63
        {
            float run = 0.f;
            for (int q = 7; q >= 0; --q) { const int c = seg * 8 + q; run += Us[c * 8 + f]; Us[c * 8 + f] = run; }
            segTU[seg * 8 + f] = run;
            float runv = 0.f;
            for (int q = 0; q < 8; ++q) { const int c = seg * 8 + q; const float tmp = Vp[c * 8 + f]; Vp[c * 8 + f] = runv; runv += tmp; }
            segTV[seg * 8 + f] = runv;
            if (t < 64) {
                float r = 0.f;
                for (int q = 7; q >= 0; --q) { const int c = t * 8 + q; r += sus[c]; sus[c] = r; }
                segSU[t] = r;
                float rv = 0.f;
                for (int q = 0; q < 8; ++q) { const int c = t * 8 + q; const float tmp = svp[c]; svp[c] = rv; rv += tmp; }
                segSV[t] = rv;
            }
        }
        __syncthreads();

        // second-level offsets
        {
            float offU = 0.f, offV = 0.f;
            for (int s = seg + 1; s < 64; ++s) offU += segTU[s * 8 + f];
            for (int s = 0; s < seg; ++s)      offV += segTV[s * 8 + f];
            for (int q = 0; q < 8; ++q) {
                const int c = seg * 8 + q;
                Us[c * 8 + f] += offU;
                Vp[c * 8 + f] += offV;
            }
            if (seg == 63) Vp[512 * 8 + f] = offV + segTV[63 * 8 + f];   // total
            if (t < 16) Us[512 * 8 + t] = 0.f;                           // pads
            if (t < 64) {
                float oU = 0.f, oV = 0.f;
                for (int s = t + 1; s < 64; ++s) oU += segSU[s];
                for (int s = 0; s < t; ++s)      oV += segSV[s];
                for (int q = 0; q < 8; ++q) { sus[t * 8 + q] += oU; svp[t * 8 + q] += oV; }
                if (t == 63) svp[512] = oV + segSV[63];
                if (t == 0) { sus[512] = 0.f; sus[513] = 0.f; }
            }
        }
        __syncthreads();

        // outputs: wave w -> 16 rows; lane -> (row-slot g, feature fo)
        const int g = lane >> 3, fo = lane & 7;
        #pragma unroll
        for (int it = 0; it < 2; ++it) {
            const int i = rg * 128 + w * 16 + it * 8 + g;
            const float s1v = s1[i];
            const unsigned thr = (f2key(-s1v) & 0xFFFFE000u) | 0x1FFFu;
            int k = 0;                         // #{p: kss[p] <= thr}
            #pragma unroll
            for (int s = NV; s > 0; s >>= 1) {
                const int nk = k + s;
                if (nk <= NV && kss[nk - 1] <= thr) k = nk;
            }
            const int c = k >> 4;              // chunk of the cut, 0..512
            float accU = 0.f, accV = 0.f, sau = 0.f, sav = 0.f;
            const int pst = c * CH;
            #pragma unroll
            for (int q = 0; q < CH; ++q) {
                const int p = pst + q;
                if (p < NV) {
                    const int j = sortedIdx[p];
                    const float wv = Wh[(size_t)j * 64 + fid * 8 + fo];
                    if (p < k) { const float v = sortedV[p]; accV = fmaf(v, wv, accV); sav += v; }
                    else       { const float u = sortedU[p]; accU = fmaf(u, wv, accU); sau += u; }
                }
            }
            const float A = __expf(s1v), B = __expf(0.2f * s1v);
            const float numer = A * (Us[(c + 1) * 8 + fo] + accU) + B * (Vp[c * 8 + fo] + accV);
            const float den   = A * (sus[c + 1] + sau)            + B * (svp[c] + sav);
            out[(size_t)i * 64 + fid * 8 + fo] = numer / den;
        }
    }
}

// ----------------------------------------------------------------
extern "C" void kernel_launch(void* const* d_in, const int* in_sizes, int n_in,
                              void* d_out, int out_size, void* d_ws, size_t ws_size,
                              hipStream_t stream) {
    (void)in_sizes; (void)n_in; (void)out_size; (void)ws_size;
    const float* h = (const float*)d_in[0];
    // d_in[1] = adj : unused by the reference computation
    const float* W = (const float*)d_in[2];
    const float* a = (const float*)d_in[3];
    float* out = (float*)d_out;

    unsigned* bar       = (unsigned*)d_ws;        // 2 barriers x 2048 dwords
    int*      sortedIdx = (int*)d_ws + 4096;
    unsigned* sortedKey = (unsigned*)d_ws + 4096 + NV;
    float* fws = (float*)d_ws + 4096 + 2 * NV;
    float* Wh      = fws;  fws += (size_t)NV * 64;
    float* s1      = fws;  fws += NV;
    float* s2g     = fws;  fws += NV;
    float* sortedU = fws;  fws += NV;
    float* sortedV = fws;  fws += NV;

    // zero barrier counters (in-graph: runs every replay)
    hipMemsetAsync(bar, 0, 4096 * sizeof(unsigned), stream);

    int coopMode = 1, lo = 0, hi = 2;
    void* args[] = {
        (void*)&h, (void*)&W, (void*)&a, (void*)&out,
        (void*)&Wh, (void*)&s1, (void*)&s2g,
        (void*)&sortedIdx, (void*)&sortedKey, (void*)&sortedU, (void*)&sortedV,
        (void*)&bar, (void*)&coopMode, (void*)&lo, (void*)&hi
    };
    hipError_t err = hipLaunchCooperativeKernel(
        (const void*)gat3, dim3(NB), dim3(NT), args, 0, stream);

    if (err != hipSuccess) {
        // fallback: one launch per phase (barriers skipped)
        for (int p = 0; p < 3; ++p) {
            hipLaunchKernelGGL(gat3, dim3(NB), dim3(NT), 0, stream,
                               h, W, a, out, Wh, s1, s2g,
                               sortedIdx, sortedKey, sortedU, sortedV,
                               bar, 0, p, p);
        }
    }
}

// Round 7
// 89.297 us; speedup vs baseline: 1.4589x; 1.4589x over previous
//
#include <hip/hip_runtime.h>

// GAT layer, N=8192, IN_F=512, OUT_F=64, alpha=0.2
// exp(lrelu(s1_i+s2_j)) factors on each side of s2_j <= -s1_i =>
// row_i = [A_i*suffixsum(exp(s2)*Wh) + B_i*prefixsum(exp(.2 s2)*Wh)] / (scalars)
// over s2 sorted ascending. O(N*F).
// 2 nodes: k1_gemm (plain; also zeroes barrier space) -> k2_main (coop:
// rank -> ONE tree barrier with hierarchical broadcast (<=8 pollers/line;
// R4/R6 showed single-poll-line barriers cost ~30us) -> output phase).

constexpr int NV  = 8192;
constexpr int FIN = 512;
constexpr int NT  = 512;      // threads/block
constexpr int CH  = 32;       // sorted positions per chunk
constexpr int NCH = 256;      // NV/CH
constexpr int NB2 = 256;      // node-2 blocks (1/CU)

__device__ __forceinline__ unsigned f2key(float x) {
    unsigned b = __float_as_uint(x);
    return (b & 0x80000000u) ? ~b : (b | 0x80000000u);  // order-preserving
}

// ================= node 1: zero barrier region + GEMM ======================
__global__ __launch_bounds__(NT, 4) void k1_gemm(
    const float* __restrict__ h, const float* __restrict__ W,
    const float* __restrict__ a, float* __restrict__ Wh,
    float* __restrict__ s1, float* __restrict__ s2g,
    unsigned* __restrict__ bar)
{
    // zero 2048 dwords of barrier space; node boundary publishes it
    if (blockIdx.x < 64 && threadIdx.x < 32)
        bar[blockIdx.x * 32 + threadIdx.x] = 0u;

    __shared__ float smem[8192];   // 32 KB W-chunk
    const int t = threadIdx.x, b = blockIdx.x;
    const int lane = t & 63, w = t >> 6;
    const int row0 = __builtin_amdgcn_readfirstlane(b * 16 + w * 2);
    float4 A0 = {0.f,0.f,0.f,0.f}, A1 = {0.f,0.f,0.f,0.f};
    const float4* Wf4 = reinterpret_cast<const float4*>(W);
    float4* S4 = reinterpret_cast<float4*>(smem);
    for (int pass = 0; pass < 4; ++pass) {
        // stage W[:, pass*128 .. +128) into LDS, rotation-swizzled
        #pragma unroll
        for (int it = 0; it < 4; ++it) {
            const int g = it * 512 + t;          // 0..2047
            const int f = g >> 5, kk4 = g & 31;
            S4[kk4 * 64 + ((f + kk4) & 63)] = Wf4[f * 128 + pass * 32 + kk4];
        }
        __syncthreads();
        const float* hb = h + (size_t)row0 * FIN + pass * 128;
        #pragma unroll 8
        for (int k4 = 0; k4 < 32; ++k4) {
            const float4 wv = S4[k4 * 64 + ((lane + k4) & 63)];
            const float4 h0 = *reinterpret_cast<const float4*>(hb + k4 * 4);
            const float4 h1 = *reinterpret_cast<const float4*>(hb + FIN + k4 * 4);
            A0.x = fmaf(h0.x, wv.x, A0.x); A0.y = fmaf(h0.y, wv.y, A0.y);
            A0.z = fmaf(h0.z, wv.z, A0.z); A0.w = fmaf(h0.w, wv.w, A0.w);
            A1.x = fmaf(h1.x, wv.x, A1.x); A1.y = fmaf(h1.y, wv.y, A1.y);
            A1.z = fmaf(h1.z, wv.z, A1.z); A1.w = fmaf(h1.w, wv.w, A1.w);
        }
        __syncthreads();
    }
    const float acc0 = (A0.x + A0.y) + (A0.z + A0.w);
    const float acc1 = (A1.x + A1.y) + (A1.z + A1.w);
    Wh[(size_t)row0 * 64 + lane] = acc0;
    Wh[(size_t)(row0 + 1) * 64 + lane] = acc1;
    const float a1 = a[lane], a2 = a[64 + lane];
    float r0s1 = acc0 * a1, r0s2 = acc0 * a2;
    float r1s1 = acc1 * a1, r1s2 = acc1 * a2;
    #pragma unroll
    for (int off = 32; off > 0; off >>= 1) {
        r0s1 += __shfl_xor(r0s1, off);
        r0s2 += __shfl_xor(r0s2, off);
        r1s1 += __shfl_xor(r1s1, off);
        r1s2 += __shfl_xor(r1s2, off);
    }
    if (lane == 0) {
        s1[row0] = r0s1;     s2g[row0] = r0s2;
        s1[row0 + 1] = r1s1; s2g[row0 + 1] = r1s2;
    }
}

// ================= node 2: rank -> tree barrier -> output ==================
// mode: 0 = rank only, 1 = output only (fallback path), 2 = both + barrier
__global__ __launch_bounds__(NT, 4) void k2_main(
    const float* __restrict__ Wh, const float* __restrict__ s1,
    const float* __restrict__ s2g,
    int* __restrict__ sortedIdx, unsigned* __restrict__ sortedKey,
    float* __restrict__ sortedU, float* __restrict__ sortedV,
    float* __restrict__ out, unsigned* __restrict__ bar, int mode)
{
    __shared__ __align__(16) unsigned char lds[69984];
    const int t = threadIdx.x, b = blockIdx.x;

    // ---------------- phase A: rank by unique key ----------------
    if (mode != 1) {
        unsigned* ks = reinterpret_cast<unsigned*>(lds);
        #pragma unroll
        for (int q = 0; q < NV / NT; ++q) {
            const int j = q * NT + t;
            ks[j] = (f2key(s2g[j]) & 0xFFFFE000u) | (unsigned)j;  // unique
        }
        __syncthreads();
        const int seg = t & 15;               // 16 threads per id
        const int id  = b * 32 + (t >> 4);
        const unsigned key = ks[id];
        int cnt = 0;
        const uint4* K4 = reinterpret_cast<const uint4*>(ks);
        #pragma unroll 4
        for (int kk = 0; kk < 128; ++kk) {
            const uint4 v = K4[kk * 16 + seg];     // contiguous across lanes
            cnt += (int)(v.x < key) + (int)(v.y < key)
                 + (int)(v.z < key) + (int)(v.w < key);
        }
        cnt += __shfl_xor(cnt, 1);
        cnt += __shfl_xor(cnt, 2);
        cnt += __shfl_xor(cnt, 4);
        cnt += __shfl_xor(cnt, 8);
        if (seg == 0) {
            sortedKey[cnt] = key;
            sortedIdx[cnt] = id;
            const float x = s2g[id];
            sortedU[cnt] = __expf(x);
            sortedV[cnt] = __expf(0.2f * x);
        }
    }

    // ---------------- tree barrier (256 blocks) ----------------
    // arrivals: c1[32] fan-8 -> c2[4] fan-8 -> c3 fan-4 (ACQ_REL RMWs)
    // broadcast: c3-setter -> f2[4] -> cluster leaders -> f1[32] -> blocks
    // poll fan-in <= 8 per line; 64B line spacing
    if (mode == 2) {
        __syncthreads();
        if (t == 0) {
            const unsigned r1 = __hip_atomic_fetch_add(bar + (b >> 3) * 16, 1u,
                                    __ATOMIC_ACQ_REL, __HIP_MEMORY_SCOPE_AGENT);
            if (r1 == 7u) {
                const unsigned r2 = __hip_atomic_fetch_add(bar + 512 + (b >> 6) * 16, 1u,
                                        __ATOMIC_ACQ_REL, __HIP_MEMORY_SCOPE_AGENT);
                if (r2 == 7u) {
                    const unsigned r3 = __hip_atomic_fetch_add(bar + 576, 1u,
                                            __ATOMIC_ACQ_REL, __HIP_MEMORY_SCOPE_AGENT);
                    if (r3 == 3u) {
                        #pragma unroll
                        for (int g = 0; g < 4; ++g)
                            __hip_atomic_store(bar + 640 + g * 16, 1u,
                                __ATOMIC_RELEASE, __HIP_MEMORY_SCOPE_AGENT);
                    }
                }
            }
            if ((b & 63) == 0) {   // cluster leader: b = 0,64,128,192
                while (__hip_atomic_load(bar + 640 + (b >> 6) * 16,
                         __ATOMIC_RELAXED, __HIP_MEMORY_SCOPE_AGENT) == 0u)
                    __builtin_amdgcn_s_sleep(2);
                (void)__hip_atomic_load(bar + 640 + (b >> 6) * 16,
                         __ATOMIC_ACQUIRE, __HIP_MEMORY_SCOPE_AGENT);
                #pragma unroll
                for (int g = 0; g < 8; ++g)
                    __hip_atomic_store(bar + 768 + ((b >> 6) * 8 + g) * 16, 1u,
                        __ATOMIC_RELEASE, __HIP_MEMORY_SCOPE_AGENT);
            }
            while (__hip_atomic_load(bar + 768 + (b >> 3) * 16,
                     __ATOMIC_RELAXED, __HIP_MEMORY_SCOPE_AGENT) == 0u)
                __builtin_amdgcn_s_sleep(2);
            (void)__hip_atomic_load(bar + 768 + (b >> 3) * 16,
                     __ATOMIC_ACQUIRE, __HIP_MEMORY_SCOPE_AGENT);
        }
        __syncthreads();
    }

    // ---------------- phase B: block = (row-group 128, feat-quarter 16) ----
    if (mode != 0) {
        unsigned* kss  = reinterpret_cast<unsigned*>(lds);        // 32768 B
        float* Us    = reinterpret_cast<float*>(lds + 32768);     // [258][16]
        float* Vp    = reinterpret_cast<float*>(lds + 49280);     // [257][16]
        float* sus   = reinterpret_cast<float*>(lds + 65728);     // [258]
        float* svp   = reinterpret_cast<float*>(lds + 66768);     // [257]
        float* segTU = reinterpret_cast<float*>(lds + 67808);     // [16][16]
        float* segTV = reinterpret_cast<float*>(lds + 68832);     // [16][16]
        float* segSU = reinterpret_cast<float*>(lds + 69856);     // [16]
        float* segSV = reinterpret_cast<float*>(lds + 69920);     // [16]

        const int fq = b & 3;      // feats [fq*16, fq*16+16)
        const int rg = b >> 2;     // rows  [rg*128, rg*128+128)

        #pragma unroll
        for (int q = 0; q < NV / NT; ++q)
            kss[q * NT + t] = sortedKey[q * NT + t];

        // chunk sums: unit = (chunk c, 4-feat group fs); 2 units/thread
        #pragma unroll
        for (int rep = 0; rep < 2; ++rep) {
            const int unit = rep * NT + t;
            const int c = unit >> 2;
            const int fs = (unit & 3) * 4;
            float au[4] = {0.f,0.f,0.f,0.f}, av[4] = {0.f,0.f,0.f,0.f};
            float su = 0.f, sv = 0.f;
            for (int q = 0; q < CH; ++q) {
                const int p = c * CH + q;
                const int j = sortedIdx[p];
                const float u = sortedU[p];
                const float v = sortedV[p];
                const float4 wv = *reinterpret_cast<const float4*>(
                                      Wh + (size_t)j * 64 + fq * 16 + fs);
                au[0]=fmaf(u,wv.x,au[0]); au[1]=fmaf(u,wv.y,au[1]);
                au[2]=fmaf(u,wv.z,au[2]); au[3]=fmaf(u,wv.w,au[3]);
                av[0]=fmaf(v,wv.x,av[0]); av[1]=fmaf(v,wv.y,av[1]);
                av[2]=fmaf(v,wv.z,av[2]); av[3]=fmaf(v,wv.w,av[3]);
                su += u; sv += v;
            }
            *reinterpret_cast<float4*>(Us + c * 16 + fs) =
                make_float4(au[0], au[1], au[2], au[3]);
            *reinterpret_cast<float4*>(Vp + c * 16 + fs) =
                make_float4(av[0], av[1], av[2], av[3]);
            if ((unit & 3) == 0) { sus[c] = su; svp[c] = sv; }
        }
        __syncthreads();

        // level-1 scans: 16 feats x 16 segs of 16 chunks (+ scalar lane)
        if (t < 256) {
            const int f = t & 15, seg = t >> 4;
            float run = 0.f;
            for (int q = 15; q >= 0; --q) {
                const int c = seg * 16 + q;
                run += Us[c * 16 + f];
                Us[c * 16 + f] = run;
            }
            segTU[seg * 16 + f] = run;
            float rv = 0.f;
            for (int q = 0; q < 16; ++q) {
                const int c = seg * 16 + q;
                const float tmp = Vp[c * 16 + f];
                Vp[c * 16 + f] = rv;
                rv += tmp;
            }
            segTV[seg * 16 + f] = rv;
        } else if (t < 272) {
            const int sg = t - 256;
            float r = 0.f;
            for (int q = 15; q >= 0; --q) { const int c = sg * 16 + q; r += sus[c]; sus[c] = r; }
            segSU[sg] = r;
            float rv = 0.f;
            for (int q = 0; q < 16; ++q) { const int c = sg * 16 + q; const float tmp = svp[c]; svp[c] = rv; rv += tmp; }
            segSV[sg] = rv;
        }
        __syncthreads();

        // level-2 offsets + boundary rows
        if (t < 256) {
            const int f = t & 15, seg = t >> 4;
            float offU = 0.f, offV = 0.f;
            for (int s = seg + 1; s < 16; ++s) offU += segTU[s * 16 + f];
            for (int s = 0; s < seg; ++s)      offV += segTV[s * 16 + f];
            for (int q = 0; q < 16; ++q) {
                const int c = seg * 16 + q;
                Us[c * 16 + f] += offU;
                Vp[c * 16 + f] += offV;
            }
        } else if (t < 272) {
            const int sg = t - 256;
            float oU = 0.f, oV = 0.f;
            for (int s = sg + 1; s < 16; ++s) oU += segSU[s];
            for (int s = 0; s < sg; ++s)      oV += segSV[s];
            for (int q = 0; q < 16; ++q) { sus[sg * 16 + q] += oU; svp[sg * 16 + q] += oV; }
        } else if (t < 288) {
            const int f = t - 272;
            Us[256 * 16 + f] = 0.f;
            Us[257 * 16 + f] = 0.f;
            float tot = 0.f;
            for (int s = 0; s < 16; ++s) tot += segTV[s * 16 + f];
            Vp[256 * 16 + f] = tot;
        } else if (t == 288) {
            sus[256] = 0.f; sus[257] = 0.f;
            float tv = 0.f;
            for (int s = 0; s < 16; ++s) tv += segSV[s];
            svp[256] = tv;
        }
        __syncthreads();

        // outputs: thread -> (row r, 4-feat group fs)
        const int r = t >> 2, fs = (t & 3) * 4;
        const int i = rg * 128 + r;
        const float s1v = s1[i];
        const unsigned thr = (f2key(-s1v) & 0xFFFFE000u) | 0x1FFFu;
        int k = 0;                             // #{p: kss[p] <= thr}
        #pragma unroll
        for (int s = NV; s > 0; s >>= 1) {
            const int nk = k + s;
            if (nk <= NV && kss[nk - 1] <= thr) k = nk;
        }
        const int c = k >> 5;                  // cut chunk, 0..256
        float accU[4] = {0.f,0.f,0.f,0.f}, accV[4] = {0.f,0.f,0.f,0.f};
        float sau = 0.f, sav = 0.f;
        const int pst = c * CH;
        for (int q = 0; q < CH; ++q) {
            const int p = pst + q;
            if (p < NV) {
                const int j = sortedIdx[p];
                const float4 wv = *reinterpret_cast<const float4*>(
                                      Wh + (size_t)j * 64 + fq * 16 + fs);
                if (p < k) {
                    const float v = sortedV[p];
                    accV[0]=fmaf(v,wv.x,accV[0]); accV[1]=fmaf(v,wv.y,accV[1]);
                    accV[2]=fmaf(v,wv.z,accV[2]); accV[3]=fmaf(v,wv.w,accV[3]);
                    sav += v;
                } else {
                    const float u = sortedU[p];
                    accU[0]=fmaf(u,wv.x,accU[0]); accU[1]=fmaf(u,wv.y,accU[1]);
                    accU[2]=fmaf(u,wv.z,accU[2]); accU[3]=fmaf(u,wv.w,accU[3]);
                    sau += u;
                }
            }
        }
        const float A = __expf(s1v), B = __expf(0.2f * s1v);
        const float den = A * (sus[c + 1] + sau) + B * (svp[c] + sav);
        const float inv = 1.f / den;
        float4 o;
        o.x = (A * (Us[(c+1)*16 + fs+0] + accU[0]) + B * (Vp[c*16 + fs+0] + accV[0])) * inv;
        o.y = (A * (Us[(c+1)*16 + fs+1] + accU[1]) + B * (Vp[c*16 + fs+1] + accV[1])) * inv;
        o.z = (A * (Us[(c+1)*16 + fs+2] + accU[2]) + B * (Vp[c*16 + fs+2] + accV[2])) * inv;
        o.w = (A * (Us[(c+1)*16 + fs+3] + accU[3]) + B * (Vp[c*16 + fs+3] + accV[3])) * inv;
        *reinterpret_cast<float4*>(out + (size_t)i * 64 + fq * 16 + fs) = o;
    }
}

// ----------------------------------------------------------------
extern "C" void kernel_launch(void* const* d_in, const int* in_sizes, int n_in,
                              void* d_out, int out_size, void* d_ws, size_t ws_size,
                              hipStream_t stream) {
    (void)in_sizes; (void)n_in; (void)out_size; (void)ws_size;
    const float* h = (const float*)d_in[0];
    // d_in[1] = adj : unused by the reference computation
    const float* W = (const float*)d_in[2];
    const float* a = (const float*)d_in[3];
    float* out = (float*)d_out;

    unsigned* bar       = (unsigned*)d_ws;          // 2048 dwords (8 KB)
    int*      sortedIdx = (int*)d_ws + 2048;
    unsigned* sortedKey = (unsigned*)d_ws + 2048 + NV;
    float* fws = (float*)d_ws + 2048 + 2 * NV;
    float* Wh      = fws;  fws += (size_t)NV * 64;
    float* s1      = fws;  fws += NV;
    float* s2g     = fws;  fws += NV;
    float* sortedU = fws;  fws += NV;
    float* sortedV = fws;  fws += NV;

    hipLaunchKernelGGL(k1_gemm, dim3(512), dim3(NT), 0, stream,
                       h, W, a, Wh, s1, s2g, bar);

    int mode = 2;
    void* args[] = {
        (void*)&Wh, (void*)&s1, (void*)&s2g,
        (void*)&sortedIdx, (void*)&sortedKey, (void*)&sortedU, (void*)&sortedV,
        (void*)&out, (void*)&bar, (void*)&mode
    };
    hipError_t err = hipLaunchCooperativeKernel(
        (const void*)k2_main, dim3(NB2), dim3(NT), args, 0, stream);

    if (err != hipSuccess) {
        // fallback: split node 2 at the barrier into two plain launches
        hipLaunchKernelGGL(k2_main, dim3(NB2), dim3(NT), 0, stream,
                           Wh, s1, s2g, sortedIdx, sortedKey, sortedU, sortedV,
                           out, bar, 0);
        hipLaunchKernelGGL(k2_main, dim3(NB2), dim3(NT), 0, stream,
                           Wh, s1, s2g, sortedIdx, sortedKey, sortedU, sortedV,
                           out, bar, 1);
    }
}

// Round 8
// 51.285 us; speedup vs baseline: 2.5402x; 1.7412x over previous
//
#include <hip/hip_runtime.h>

// GAT layer, N=8192, IN_F=512, OUT_F=64, alpha=0.2
// exp(lrelu(s1_i+s2_j)) factors on each side of s2_j <= thr_i = -s1_i =>
// row_i = [A_i*Sum_{s2>thr} exp(s2)Wh + B_i*Sum_{s2<=thr} exp(.2 s2)Wh] / (scalars)
// TWO plain kernels (every grid-sync variant measured ~28us; node slot 13.5us):
//   k1: Wh = h@W^T, s1, s2
//   k2: per-block PRIVATE bucket-sort of s2 in LDS (erff-spread buckets ->
//       ~2 ids/bucket), chunk sums + LDS scans for a 16-feature slice,
//       exact compares in the threshold's bucket, outputs 128 rows.
// No global sorted arrays, no barriers, no cooperative launch.

constexpr int NV  = 8192;
constexpr int FIN = 512;
constexpr int NT  = 512;
constexpr int CH  = 32;      // positions per chunk
constexpr int NCH = 256;     // NV/CH
constexpr int NBK = 4096;    // value buckets

// ================= k1: Wh = h @ W^T ; s1 ; s2 =============================
__global__ __launch_bounds__(NT, 4) void k1_gemm(
    const float* __restrict__ h, const float* __restrict__ W,
    const float* __restrict__ a, float* __restrict__ Wh,
    float* __restrict__ s1, float* __restrict__ s2g)
{
    __shared__ float smem[8192];   // 32 KB W-chunk
    const int t = threadIdx.x, b = blockIdx.x;
    const int lane = t & 63, w = t >> 6;
    const int row0 = __builtin_amdgcn_readfirstlane(b * 16 + w * 2);
    float4 A0 = {0.f,0.f,0.f,0.f}, A1 = {0.f,0.f,0.f,0.f};
    const float4* Wf4 = reinterpret_cast<const float4*>(W);
    float4* S4 = reinterpret_cast<float4*>(smem);
    for (int pass = 0; pass < 4; ++pass) {
        // stage W[:, pass*128 .. +128) into LDS, rotation-swizzled
        #pragma unroll
        for (int it = 0; it < 4; ++it) {
            const int g = it * 512 + t;          // 0..2047
            const int f = g >> 5, kk4 = g & 31;
            S4[kk4 * 64 + ((f + kk4) & 63)] = Wf4[f * 128 + pass * 32 + kk4];
        }
        __syncthreads();
        const float* hb = h + (size_t)row0 * FIN + pass * 128;
        #pragma unroll 8
        for (int k4 = 0; k4 < 32; ++k4) {
            const float4 wv = S4[k4 * 64 + ((lane + k4) & 63)];
            const float4 h0 = *reinterpret_cast<const float4*>(hb + k4 * 4);
            const float4 h1 = *reinterpret_cast<const float4*>(hb + FIN + k4 * 4);
            A0.x = fmaf(h0.x, wv.x, A0.x); A0.y = fmaf(h0.y, wv.y, A0.y);
            A0.z = fmaf(h0.z, wv.z, A0.z); A0.w = fmaf(h0.w, wv.w, A0.w);
            A1.x = fmaf(h1.x, wv.x, A1.x); A1.y = fmaf(h1.y, wv.y, A1.y);
            A1.z = fmaf(h1.z, wv.z, A1.z); A1.w = fmaf(h1.w, wv.w, A1.w);
        }
        __syncthreads();
    }
    const float acc0 = (A0.x + A0.y) + (A0.z + A0.w);
    const float acc1 = (A1.x + A1.y) + (A1.z + A1.w);
    Wh[(size_t)row0 * 64 + lane] = acc0;
    Wh[(size_t)(row0 + 1) * 64 + lane] = acc1;
    const float a1 = a[lane], a2 = a[64 + lane];
    float r0s1 = acc0 * a1, r0s2 = acc0 * a2;
    float r1s1 = acc1 * a1, r1s2 = acc1 * a2;
    #pragma unroll
    for (int off = 32; off > 0; off >>= 1) {
        r0s1 += __shfl_xor(r0s1, off);
        r0s2 += __shfl_xor(r0s2, off);
        r1s1 += __shfl_xor(r1s1, off);
        r1s2 += __shfl_xor(r1s2, off);
    }
    if (lane == 0) {
        s1[row0] = r0s1;     s2g[row0] = r0s2;
        s1[row0 + 1] = r1s1; s2g[row0 + 1] = r1s2;
    }
}

// monotone spreading map: Gaussian s2 -> ~uniform bucket index
__device__ __forceinline__ int bucketOf(float x, float mu, float is) {
    const float c = erff((x - mu) * is * 0.70710678f);   // in [-1,1]
    const int b = (int)((c * 0.5f + 0.5f) * 4096.0f);
    return min(max(b, 0), NBK - 1);
}

// ================= k2: private bucket-sort + slice output ==================
// block b: fq = b&3 -> features [fq*16,+16); rg = b>>2 -> rows [rg*128,+128)
__global__ __launch_bounds__(NT, 1) void k2_out(
    const float* __restrict__ Wh, const float* __restrict__ s1,
    const float* __restrict__ s2g, float* __restrict__ out)
{
    __shared__ __align__(16) unsigned char pool[102784];
    float*          s2f  = reinterpret_cast<float*>(pool);              // 32768
    unsigned*       Bst  = reinterpret_cast<unsigned*>(pool + 32768);   // 16384 (4096)
    unsigned short* sid  = reinterpret_cast<unsigned short*>(pool + 49152); // 16384
    float*          Us   = reinterpret_cast<float*>(pool + 65536);      // [257][16]
    float*          Vp   = reinterpret_cast<float*>(pool + 81984);      // [257][16]
    float*          sus  = reinterpret_cast<float*>(pool + 98432);      // [257]
    float*          svp  = reinterpret_cast<float*>(pool + 99472);      // [257]
    float*          segTU= reinterpret_cast<float*>(pool + 100512);     // [16][16]
    float*          segTV= reinterpret_cast<float*>(pool + 101536);     // [16][16]
    float*          segSU= reinterpret_cast<float*>(pool + 102560);     // [16]
    float*          segSV= reinterpret_cast<float*>(pool + 102624);     // [16]
    float*          fscr = reinterpret_cast<float*>(pool + 102688);     // [16]
    unsigned*       uscr = reinterpret_cast<unsigned*>(pool + 102752);  // [8]

    const int t = threadIdx.x, b = blockIdx.x;
    const int lane = t & 63, w = t >> 6;
    const int fq = b & 3;
    const int rg = b >> 2;

    // ---- stage s2 into LDS + moments ----
    float S = 0.f, SQ = 0.f;
    #pragma unroll
    for (int q = 0; q < 4; ++q) {
        const int idx = q * 2048 + t * 4;
        const float4 v = *reinterpret_cast<const float4*>(s2g + idx);
        *reinterpret_cast<float4*>(s2f + idx) = v;
        S += (v.x + v.y) + (v.z + v.w);
        SQ += (v.x*v.x + v.y*v.y) + (v.z*v.z + v.w*v.w);
    }
    #pragma unroll
    for (int off = 32; off > 0; off >>= 1) {
        S  += __shfl_xor(S, off);
        SQ += __shfl_xor(SQ, off);
    }
    if (lane == 0) { fscr[w] = S; fscr[8 + w] = SQ; }
    __syncthreads();
    float Stot = 0.f, SQtot = 0.f;
    #pragma unroll
    for (int q = 0; q < 8; ++q) { Stot += fscr[q]; SQtot += fscr[8 + q]; }
    const float mu = Stot * (1.f / NV);
    const float var = fmaxf(SQtot * (1.f / NV) - mu * mu, 1e-30f);
    const float isg = rsqrtf(var);

    // ---- histogram ----
    #pragma unroll
    for (int e = 0; e < 8; ++e) Bst[t * 8 + e] = 0u;
    __syncthreads();
    #pragma unroll
    for (int q = 0; q < NV / NT; ++q) {
        const int j = q * NT + t;
        atomicAdd(&Bst[bucketOf(s2f[j], mu, isg)], 1u);
    }
    __syncthreads();

    // ---- exclusive scan of 4096 counts (8/thread + block scan) ----
    {
        unsigned cnt[8]; unsigned tt = 0u;
        #pragma unroll
        for (int e = 0; e < 8; ++e) { cnt[e] = Bst[t * 8 + e]; tt += cnt[e]; }
        unsigned x = tt;
        #pragma unroll
        for (int d = 1; d < 64; d <<= 1) {
            const unsigned y = __shfl_up(x, d);
            if (lane >= d) x += y;
        }
        if (lane == 63) uscr[w] = x;
        __syncthreads();
        unsigned wb = 0u;
        for (int q = 0; q < 8; ++q) if (q < w) wb += uscr[q];
        unsigned run = wb + x - tt;    // exclusive base
        #pragma unroll
        for (int e = 0; e < 8; ++e) { const unsigned c = cnt[e]; Bst[t * 8 + e] = run; run += c; }
    }
    __syncthreads();

    // ---- scatter: sid = ids in bucket order; Bst[b] becomes end-of-bucket ----
    #pragma unroll
    for (int q = 0; q < NV / NT; ++q) {
        const int j = q * NT + t;
        const unsigned slot = atomicAdd(&Bst[bucketOf(s2f[j], mu, isg)], 1u);
        sid[slot] = (unsigned short)j;
    }
    __syncthreads();

    // ---- chunk sums: unit = (chunk c, 4-feat group fs); 2 units/thread ----
    #pragma unroll
    for (int rep = 0; rep < 2; ++rep) {
        const int unit = rep * NT + t;
        const int c = unit >> 2;
        const int fs = (unit & 3) * 4;
        float au[4] = {0.f,0.f,0.f,0.f}, av[4] = {0.f,0.f,0.f,0.f};
        float su = 0.f, sv = 0.f;
        for (int q = 0; q < CH; ++q) {
            const int p = c * CH + q;
            const int j = sid[p];
            const float x = s2f[j];
            const float u = __expf(x);
            const float v = __expf(0.2f * x);
            const float4 wv = *reinterpret_cast<const float4*>(
                                  Wh + (size_t)j * 64 + fq * 16 + fs);
            au[0]=fmaf(u,wv.x,au[0]); au[1]=fmaf(u,wv.y,au[1]);
            au[2]=fmaf(u,wv.z,au[2]); au[3]=fmaf(u,wv.w,au[3]);
            av[0]=fmaf(v,wv.x,av[0]); av[1]=fmaf(v,wv.y,av[1]);
            av[2]=fmaf(v,wv.z,av[2]); av[3]=fmaf(v,wv.w,av[3]);
            su += u; sv += v;
        }
        *reinterpret_cast<float4*>(Us + c * 16 + fs) = make_float4(au[0],au[1],au[2],au[3]);
        *reinterpret_cast<float4*>(Vp + c * 16 + fs) = make_float4(av[0],av[1],av[2],av[3]);
        if ((unit & 3) == 0) { sus[c] = su; svp[c] = sv; }
    }
    __syncthreads();

    // ---- level-1 scans: 16 feats x 16 segs of 16 chunks (+ scalar lane) ----
    if (t < 256) {
        const int f = t & 15, seg = t >> 4;
        float run = 0.f;
        for (int q = 15; q >= 0; --q) {
            const int c = seg * 16 + q;
            run += Us[c * 16 + f];
            Us[c * 16 + f] = run;
        }
        segTU[seg * 16 + f] = run;
        float rv = 0.f;
        for (int q = 0; q < 16; ++q) {
            const int c = seg * 16 + q;
            const float tmp = Vp[c * 16 + f];
            Vp[c * 16 + f] = rv;
            rv += tmp;
        }
        segTV[seg * 16 + f] = rv;
    } else if (t < 272) {
        const int sg = t - 256;
        float r = 0.f;
        for (int q = 15; q >= 0; --q) { const int c = sg * 16 + q; r += sus[c]; sus[c] = r; }
        segSU[sg] = r;
        float rv = 0.f;
        for (int q = 0; q < 16; ++q) { const int c = sg * 16 + q; const float tmp = svp[c]; svp[c] = rv; rv += tmp; }
        segSV[sg] = rv;
    }
    __syncthreads();

    // ---- level-2 offsets + boundary entries ----
    if (t < 256) {
        const int f = t & 15, seg = t >> 4;
        float offU = 0.f, offV = 0.f;
        for (int s = seg + 1; s < 16; ++s) offU += segTU[s * 16 + f];
        for (int s = 0; s < seg; ++s)      offV += segTV[s * 16 + f];
        for (int q = 0; q < 16; ++q) {
            const int c = seg * 16 + q;
            Us[c * 16 + f] += offU;
            Vp[c * 16 + f] += offV;
        }
    } else if (t < 272) {
        const int sg = t - 256;
        float oU = 0.f, oV = 0.f;
        for (int s = sg + 1; s < 16; ++s) oU += segSU[s];
        for (int s = 0; s < sg; ++s)      oV += segSV[s];
        for (int q = 0; q < 16; ++q) { sus[sg * 16 + q] += oU; svp[sg * 16 + q] += oV; }
    } else if (t < 288) {
        const int f = t - 272;
        Us[256 * 16 + f] = 0.f;
        float tot = 0.f;
        for (int s = 0; s < 16; ++s) tot += segTV[s * 16 + f];
        Vp[256 * 16 + f] = tot;
    } else if (t == 288) {
        float tv = 0.f;
        for (int s = 0; s < 16; ++s) tv += segSV[s];
        sus[256] = 0.f;
        svp[256] = tv;
    }
    __syncthreads();

    // ---- outputs: thread -> (row r, 4-feat group fs) ----
    const int r = t >> 2, fs = (t & 3) * 4;
    const int i = rg * 128 + r;
    const float s1v = s1[i];
    const float thr = -s1v;
    const int bt = bucketOf(thr, mu, isg);
    const unsigned K0 = bt ? Bst[bt - 1] : 0u;     // start of thr's bucket
    const unsigned K1 = Bst[bt];                   // end of thr's bucket
    const int c0   = (int)(K0 >> 5);
    const int cEnd = (int)((K1 + 31u) >> 5);
    float accU[4] = {0.f,0.f,0.f,0.f}, accV[4] = {0.f,0.f,0.f,0.f};
    float sau = 0.f, sav = 0.f;
    for (int p = c0 * CH; p < cEnd * CH; ++p) {
        const int j = sid[p];
        const float x = s2f[j];
        const float4 wv = *reinterpret_cast<const float4*>(
                              Wh + (size_t)j * 64 + fq * 16 + fs);
        const bool isV = ((unsigned)p < K0) | (((unsigned)p < K1) & (x <= thr));
        if (isV) {
            const float v = __expf(0.2f * x);
            accV[0]=fmaf(v,wv.x,accV[0]); accV[1]=fmaf(v,wv.y,accV[1]);
            accV[2]=fmaf(v,wv.z,accV[2]); accV[3]=fmaf(v,wv.w,accV[3]);
            sav += v;
        } else {
            const float u = __expf(x);
            accU[0]=fmaf(u,wv.x,accU[0]); accU[1]=fmaf(u,wv.y,accU[1]);
            accU[2]=fmaf(u,wv.z,accU[2]); accU[3]=fmaf(u,wv.w,accU[3]);
            sau += u;
        }
    }
    const float A  = __expf(s1v);
    const float Bc = __expf(0.2f * s1v);
    const float den = A * (sus[cEnd] + sau) + Bc * (svp[c0] + sav);
    const float inv = 1.f / den;
    float4 o;
    o.x = (A * (Us[cEnd*16 + fs+0] + accU[0]) + Bc * (Vp[c0*16 + fs+0] + accV[0])) * inv;
    o.y = (A * (Us[cEnd*16 + fs+1] + accU[1]) + Bc * (Vp[c0*16 + fs+1] + accV[1])) * inv;
    o.z = (A * (Us[cEnd*16 + fs+2] + accU[2]) + Bc * (Vp[c0*16 + fs+2] + accV[2])) * inv;
    o.w = (A * (Us[cEnd*16 + fs+3] + accU[3]) + Bc * (Vp[c0*16 + fs+3] + accV[3])) * inv;
    *reinterpret_cast<float4*>(out + (size_t)i * 64 + fq * 16 + fs) = o;
}

// ----------------------------------------------------------------
extern "C" void kernel_launch(void* const* d_in, const int* in_sizes, int n_in,
                              void* d_out, int out_size, void* d_ws, size_t ws_size,
                              hipStream_t stream) {
    (void)in_sizes; (void)n_in; (void)out_size; (void)ws_size;
    const float* h = (const float*)d_in[0];
    // d_in[1] = adj : unused by the reference computation
    const float* W = (const float*)d_in[2];
    const float* a = (const float*)d_in[3];
    float* out = (float*)d_out;

    float* Wh  = (float*)d_ws;                 // 8192*64
    float* s1  = Wh + (size_t)NV * 64;         // 8192
    float* s2g = s1 + NV;                      // 8192

    hipLaunchKernelGGL(k1_gemm, dim3(512), dim3(NT), 0, stream,
                       h, W, a, Wh, s1, s2g);
    hipLaunchKernelGGL(k2_out, dim3(256), dim3(NT), 0, stream,
                       Wh, s1, s2g, out);
}